// Round 7
// baseline (32938.605 us; speedup 1.0000x reference)
//
#include <hip/hip_runtime.h>
#include <hip/hip_bf16.h>

// 2-layer GRU encoder, T=4096, H=1024.
// v7: embed -> bf16-convert(whh) -> ONE fused persistent kernel (no GEMM).
// 256 WGs (1/CU), 8 units each; 128 WGs per layer (XCD-split by blockIdx%8).
// Per WG: whh rows (24x1024) LDS-resident in bf16; gi computed on the fly
// by dedicated waves (wih f32 from L2, overlapped); tagged-u64 h exchange.

#define TT    4096
#define HDIM  1024
#define SBS   512
#define LWG   128        // WGs per layer
#define FSTR  16         // flag stride in words (64B)
typedef unsigned short ushort_t;
typedef unsigned long long u64;

// ---------------- embedding gather ----------------
__global__ void embed_kernel(const int* __restrict__ idx,
                             const float* __restrict__ emb,
                             float* __restrict__ x) {
    int t = blockIdx.x;
    int row = idx[t];
    const float4* src = reinterpret_cast<const float4*>(emb + (size_t)row * HDIM);
    float4* dst = reinterpret_cast<float4*>(x + (size_t)t * HDIM);
    dst[threadIdx.x] = src[threadIdx.x];
}

// ---------------- f32 -> bf16 (RNE) weight convert ----------------
__device__ __forceinline__ ushort_t f2bf(float f) {
    unsigned u = __float_as_uint(f);
    return (ushort_t)((u + 0x7FFFu + ((u >> 16) & 1u)) >> 16);
}
__global__ void conv_bf16(const float* __restrict__ w,
                          ushort_t* __restrict__ o, int n4) {
    int i = blockIdx.x * blockDim.x + threadIdx.x;
    if (i < n4) {
        float4 v = reinterpret_cast<const float4*>(w)[i];
        u64 r = (u64)f2bf(v.x) | ((u64)f2bf(v.y) << 16)
              | ((u64)f2bf(v.z) << 32) | ((u64)f2bf(v.w) << 48);
        reinterpret_cast<u64*>(o)[i] = r;
    }
}

// ---------------- fused scan v7 ----------------
__device__ __forceinline__ float dot4(float4 a, float4 b) {
    return fmaf(a.x, b.x, fmaf(a.y, b.y, fmaf(a.z, b.z, a.w * b.w)));
}
__device__ __forceinline__ float fsig(float x) { return 1.f / (1.f + __expf(-x)); }
__device__ __forceinline__ float ftanh(float x) {
    return fmaf(-2.f, 1.f / (1.f + __expf(2.f * x)), 1.f);
}
__device__ __forceinline__ float bflo(unsigned u) { return __uint_as_float(u << 16); }
__device__ __forceinline__ float bfhi(unsigned u) { return __uint_as_float(u & 0xffff0000u); }
__device__ __forceinline__ u64 pack_h(unsigned seq, float h) {
    return ((u64)seq << 32) | (u64)__float_as_uint(h);
}
__device__ __forceinline__ u64 poll_h(const u64* p, unsigned need) {
    u64 v = __hip_atomic_load(p, __ATOMIC_RELAXED, __HIP_MEMORY_SCOPE_AGENT);
    while ((unsigned)(v >> 32) < need)
        v = __hip_atomic_load(p, __ATOMIC_RELAXED, __HIP_MEMORY_SCOPE_AGENT);
    return v;
}

__global__ __launch_bounds__(SBS, 1)
void gru_fused(const float* __restrict__ x,    // [T,H] embed out
               float* ys0,                     // [T,H] layer0 out (agent-coherent)
               const ushort_t* __restrict__ wbf, // [2][3H][H] bf16 whh
               const float* __restrict__ wih0, // [3H,H]
               const float* __restrict__ wih1, // [3H,H]
               const float* __restrict__ bih0, const float* __restrict__ bhh0,
               const float* __restrict__ bih1, const float* __restrict__ bhh1,
               float* __restrict__ out,        // [T*H + 2H]
               u64* h0t, u64* h1t,             // [2][H] tagged
               unsigned* flags0) {             // [2][LWG*FSTR]
    const int b   = blockIdx.x;
    const bool L0 = (b & 4) == 0;                      // XCDs 0-3 vs 4-7
    const int g   = L0 ? ((b & 7) * 32 + (b >> 3))
                       : (((b & 7) - 4) * 32 + (b >> 3));   // 0..127
    const int u0  = g * 8;
    const int tid = threadIdx.x;
    const int wv  = tid >> 6;
    const int ln  = tid & 63;

    __shared__ __align__(16) ushort_t lds_w[24 * 1032];  // 24 rows, 8-ushort pad
    __shared__ __align__(16) float lds_hf[HDIM];
    __shared__ __align__(16) float lds_y[2][HDIM];
    __shared__ float lds_gi[2][24];
    __shared__ float lds_gh[24];

    const ushort_t* wsel = wbf + (L0 ? 0 : (size_t)3 * HDIM * HDIM);
    const float*   winp  = L0 ? wih0 : wih1;
    const float*   xsrc  = L0 ? x : ys0;
    u64*           hT    = L0 ? h0t : h1t;

    // ---- load whh rows -> LDS (bf16) ----
    for (int i = tid; i < 24 * 128; i += SBS) {
        int r = i >> 7, c = i & 127;
        int R = (r >> 3) * HDIM + u0 + (r & 7);
        uint4 v = reinterpret_cast<const uint4*>(wsel + (size_t)R * HDIM)[c];
        reinterpret_cast<uint4*>(lds_w + r * 1032)[c] = v;
    }
    // h(0) = 0
    reinterpret_cast<float2*>(lds_hf)[tid] = float2{0.f, 0.f};

    // biases (lanes 0..7)
    float c_bir = 0.f, c_biz = 0.f, c_bin = 0.f;
    float c_bhr = 0.f, c_bhz = 0.f, c_bhn = 0.f;
    float h_own = 0.f;
    if (tid < 8) {
        const int u = u0 + tid;
        const float* bi = L0 ? bih0 : bih1;
        const float* bh = L0 ? bhh0 : bhh1;
        c_bir = bi[u]; c_biz = bi[HDIM + u]; c_bin = bi[2 * HDIM + u];
        c_bhr = bh[u]; c_bhz = bh[HDIM + u]; c_bhn = bh[2 * HDIM + u];
    }
    __syncthreads();

    // ---- prologue: stage input(0); gi(0); stage input(1) ----
    if (wv == 6) {
        if (!L0) {
            const unsigned* f0 = flags0 + 0 * (LWG * FSTR);
            while (__hip_atomic_load(f0 + ln * FSTR, __ATOMIC_RELAXED, __HIP_MEMORY_SCOPE_AGENT) < 1u) {}
            while (__hip_atomic_load(f0 + (ln + 64) * FSTR, __ATOMIC_RELAXED, __HIP_MEMORY_SCOPE_AGENT) < 1u) {}
        }
        const u64* s8 = reinterpret_cast<const u64*>(xsrc);
        u64* d8 = reinterpret_cast<u64*>(lds_y[0]);
#pragma unroll
        for (int c = 0; c < 4; ++c) {
            int i0 = c * 128 + ln * 2;
            d8[i0]     = __hip_atomic_load(s8 + i0,     __ATOMIC_RELAXED, __HIP_MEMORY_SCOPE_AGENT);
            d8[i0 + 1] = __hip_atomic_load(s8 + i0 + 1, __ATOMIC_RELAXED, __HIP_MEMORY_SCOPE_AGENT);
        }
    }
    __syncthreads();

    if (wv >= 3 && wv < 6) {   // gi(0) from lds_y[0]
        const int srow = (wv - 3) * 8 + (ln >> 3);
        const int l8 = ln & 7;
        const int R = (srow >> 3) * HDIM + u0 + (srow & 7);
        const float4* wr4 = reinterpret_cast<const float4*>(winp + (size_t)R * HDIM);
        const float4* ly4 = reinterpret_cast<const float4*>(lds_y[0]);
        float p = 0.f;
#pragma unroll
        for (int j = 0; j < 16; ++j) {
            p += dot4(wr4[j * 16 + l8 * 2],     ly4[j * 16 + l8 * 2]);
            p += dot4(wr4[j * 16 + l8 * 2 + 1], ly4[j * 16 + l8 * 2 + 1]);
        }
        p += __shfl_xor(p, 1); p += __shfl_xor(p, 2); p += __shfl_xor(p, 4);
        if (l8 == 0) lds_gi[0][srow] = p;
    }
    if (wv == 6 && TT > 1) {   // stage input(1) -> lds_y[1]
        if (!L0) {
            const unsigned* f1 = flags0 + 1 * (LWG * FSTR);
            while (__hip_atomic_load(f1 + ln * FSTR, __ATOMIC_RELAXED, __HIP_MEMORY_SCOPE_AGENT) < 2u) {}
            while (__hip_atomic_load(f1 + (ln + 64) * FSTR, __ATOMIC_RELAXED, __HIP_MEMORY_SCOPE_AGENT) < 2u) {}
        }
        const u64* s8 = reinterpret_cast<const u64*>(xsrc + (size_t)HDIM);
        u64* d8 = reinterpret_cast<u64*>(lds_y[1]);
#pragma unroll
        for (int c = 0; c < 4; ++c) {
            int i0 = c * 128 + ln * 2;
            d8[i0]     = __hip_atomic_load(s8 + i0,     __ATOMIC_RELAXED, __HIP_MEMORY_SCOPE_AGENT);
            d8[i0 + 1] = __hip_atomic_load(s8 + i0 + 1, __ATOMIC_RELAXED, __HIP_MEMORY_SCOPE_AGENT);
        }
    }
    __syncthreads();

    // ---- main loop ----
    for (int t = 0; t < TT; ++t) {
        // phase A
        if (wv < 3) {          // whh(bf16 LDS) . h(f32 LDS broadcast)
            const int srow = wv * 8 + (ln >> 3);
            const int l8 = ln & 7;
            const ushort_t* wr = lds_w + srow * 1032;
            const float4* lh4 = reinterpret_cast<const float4*>(lds_hf);
            float p = 0.f;
#pragma unroll
            for (int j = 0; j < 16; ++j) {
                uint4 wq = reinterpret_cast<const uint4*>(wr)[j * 8 + l8];
                float4 ha = lh4[j * 16 + l8 * 2];
                float4 hb = lh4[j * 16 + l8 * 2 + 1];
                p = fmaf(bflo(wq.x), ha.x, p); p = fmaf(bfhi(wq.x), ha.y, p);
                p = fmaf(bflo(wq.y), ha.z, p); p = fmaf(bfhi(wq.y), ha.w, p);
                p = fmaf(bflo(wq.z), hb.x, p); p = fmaf(bfhi(wq.z), hb.y, p);
                p = fmaf(bflo(wq.w), hb.z, p); p = fmaf(bfhi(wq.w), hb.w, p);
            }
            p += __shfl_xor(p, 1); p += __shfl_xor(p, 2); p += __shfl_xor(p, 4);
            if (l8 == 0) lds_gh[srow] = p;
        } else if (wv < 6) {   // wih(f32 L2) . input(t+1)  -> gi(t+1)
            const int srow = (wv - 3) * 8 + (ln >> 3);
            const int l8 = ln & 7;
            const int R = (srow >> 3) * HDIM + u0 + (srow & 7);
            const float4* wr4 = reinterpret_cast<const float4*>(winp + (size_t)R * HDIM);
            const float4* ly4 = reinterpret_cast<const float4*>(lds_y[(t + 1) & 1]);
            float p = 0.f;
#pragma unroll
            for (int j = 0; j < 16; ++j) {
                p += dot4(wr4[j * 16 + l8 * 2],     ly4[j * 16 + l8 * 2]);
                p += dot4(wr4[j * 16 + l8 * 2 + 1], ly4[j * 16 + l8 * 2 + 1]);
            }
            p += __shfl_xor(p, 1); p += __shfl_xor(p, 2); p += __shfl_xor(p, 4);
            if (l8 == 0) lds_gi[(t + 1) & 1][srow] = p;
        } else if (wv == 6) {  // stage input(t+2) -> lds_y[t&1]
            const int s = t + 2;
            if (s < TT) {
                if (!L0) {
                    const unsigned* f = flags0 + (s & 1) * (LWG * FSTR);
                    const unsigned need = (unsigned)(s + 1);
                    while (__hip_atomic_load(f + ln * FSTR, __ATOMIC_RELAXED, __HIP_MEMORY_SCOPE_AGENT) < need) {}
                    while (__hip_atomic_load(f + (ln + 64) * FSTR, __ATOMIC_RELAXED, __HIP_MEMORY_SCOPE_AGENT) < need) {}
                }
                const u64* s8 = reinterpret_cast<const u64*>(xsrc + (size_t)s * HDIM);
                u64* d8 = reinterpret_cast<u64*>(lds_y[t & 1]);
#pragma unroll
                for (int c = 0; c < 4; ++c) {
                    int i0 = c * 128 + ln * 2;
                    d8[i0]     = __hip_atomic_load(s8 + i0,     __ATOMIC_RELAXED, __HIP_MEMORY_SCOPE_AGENT);
                    d8[i0 + 1] = __hip_atomic_load(s8 + i0 + 1, __ATOMIC_RELAXED, __HIP_MEMORY_SCOPE_AGENT);
                }
            }
        }
        __syncthreads();   // S1

        // phase B: gates on lanes 0..7
        if (tid < 8) {
            const int u = u0 + tid;
            const float gr = lds_gi[t & 1][tid]      + c_bir;
            const float gz = lds_gi[t & 1][8 + tid]  + c_biz;
            const float gn = lds_gi[t & 1][16 + tid] + c_bin;
            const float hr = lds_gh[tid]      + c_bhr;
            const float hz = lds_gh[8 + tid]  + c_bhz;
            const float hn = lds_gh[16 + tid] + c_bhn;
            const float r = fsig(gr + hr);
            const float z = fsig(gz + hz);
            const float n = ftanh(gn + r * hn);
            const float h_new = (1.f - z) * n + z * h_own;
            h_own = h_new;
            __hip_atomic_store(hT + ((t + 1) & 1) * HDIM + u,
                               pack_h((unsigned)(t + 1), h_new),
                               __ATOMIC_RELAXED, __HIP_MEMORY_SCOPE_AGENT);
            if (L0) {
                __hip_atomic_store(ys0 + (size_t)t * HDIM + u, h_new,
                                   __ATOMIC_RELAXED, __HIP_MEMORY_SCOPE_AGENT);
            } else {
                out[(size_t)t * HDIM + u] = h_new;
            }
            if (t == TT - 1) out[(size_t)TT * HDIM + (L0 ? 0 : HDIM) + u] = h_new;
        }
        if (L0 && tid == 0) {
            __threadfence();
            __hip_atomic_store(flags0 + (t & 1) * (LWG * FSTR) + g * FSTR,
                               (unsigned)(t + 1),
                               __ATOMIC_RELAXED, __HIP_MEMORY_SCOPE_AGENT);
        }

        // phase D: all threads poll own 2 units of h(t+1)
        if (t + 1 < TT) {
            const unsigned need = (unsigned)(t + 1);
            const u64* hp = hT + ((t + 1) & 1) * HDIM;
            u64 v0 = poll_h(hp + 2 * tid, need);
            u64 v1 = poll_h(hp + 2 * tid + 1, need);
            float2 hv;
            hv.x = __uint_as_float((unsigned)v0);
            hv.y = __uint_as_float((unsigned)v1);
            reinterpret_cast<float2*>(lds_hf)[tid] = hv;
        }
        __syncthreads();   // S2
    }
}

// ---------------- launch ----------------
extern "C" void kernel_launch(void* const* d_in, const int* in_sizes, int n_in,
                              void* d_out, int out_size, void* d_ws, size_t ws_size,
                              hipStream_t stream) {
    const int*   idx = (const int*)d_in[0];
    const float* emb = (const float*)d_in[1];
    const float* wih = (const float*)d_in[2];
    const float* whh = (const float*)d_in[3];
    const float* bih = (const float*)d_in[4];
    const float* bhh = (const float*)d_in[5];
    float* out = (float*)d_out;

    float* x   = (float*)d_ws;                         // [T,H]
    float* ys0 = x + (size_t)TT * HDIM;                // [T,H]
    ushort_t* wbf = (ushort_t*)(ys0 + (size_t)TT * HDIM);   // [2*3H*H]
    char* ctrl = (char*)(wbf + (size_t)2 * 3 * HDIM * HDIM);
    u64* h0t = (u64*)ctrl;                             // [2][H]
    u64* h1t = h0t + 2 * HDIM;                         // [2][H]
    unsigned* flags0 = (unsigned*)(h1t + 2 * HDIM);    // [2][LWG*FSTR]
    size_t ctrl_bytes = (size_t)(4 * HDIM) * 8 + (size_t)(2 * LWG * FSTR) * 4;

    hipMemsetAsync(ctrl, 0, ctrl_bytes, stream);

    embed_kernel<<<TT, 256, 0, stream>>>(idx, emb, x);

    const int n4 = 2 * 3 * HDIM * HDIM / 4;
    conv_bf16<<<(n4 + 255) / 256, 256, 0, stream>>>(whh, wbf, n4);

    const size_t wstride = (size_t)3 * HDIM * HDIM;
    const size_t bstride = (size_t)3 * HDIM;

    gru_fused<<<256, SBS, 0, stream>>>(
        x, ys0, wbf,
        wih, wih + wstride,
        bih, bhh, bih + bstride, bhh + bstride,
        out, h0t, h1t, flags0);
}

// Round 8
// 32536.627 us; speedup vs baseline: 1.0124x; 1.0124x over previous
//
#include <hip/hip_runtime.h>
#include <hip/hip_bf16.h>

// 2-layer GRU encoder, T=4096, H=1024.
// v8: embed -> bf16 weight convert -> ONE fused persistent kernel (no GEMM).
// 256 WGs (1/CU, 108KB LDS), 8 h-units each; 128 WGs/layer (L0: XCD0-3).
// whh AND wih slices LDS-resident bf16 (24 rows each). One row per WAVE:
// lane ln owns k-chunk {j*256+ln*4+0..3}; every LDS access has consecutive
// lanes at consecutive addresses -> conflict-free by construction.
// Tagged-u64 h exchange (data-in-tag), 2 syncthreads/step.

#define TT    4096
#define HDIM  1024
#define LWG   128        // WGs per layer
#define SBS   512
#define FSTR  16         // flag stride words (64B)
typedef unsigned short ushort_t;
typedef unsigned long long u64;

// ---------------- embedding gather ----------------
__global__ void embed_kernel(const int* __restrict__ idx,
                             const float* __restrict__ emb,
                             float* __restrict__ x) {
    int t = blockIdx.x;
    int row = idx[t];
    const float4* src = reinterpret_cast<const float4*>(emb + (size_t)row * HDIM);
    float4* dst = reinterpret_cast<float4*>(x + (size_t)t * HDIM);
    dst[threadIdx.x] = src[threadIdx.x];
}

// ---------------- f32 -> bf16 (RNE) convert ----------------
__device__ __forceinline__ ushort_t f2bf(float f) {
    unsigned u = __float_as_uint(f);
    return (ushort_t)((u + 0x7FFFu + ((u >> 16) & 1u)) >> 16);
}
__global__ void conv_bf16(const float* __restrict__ w,
                          ushort_t* __restrict__ o, int n4) {
    int i = blockIdx.x * blockDim.x + threadIdx.x;
    if (i < n4) {
        float4 v = reinterpret_cast<const float4*>(w)[i];
        u64 r = (u64)f2bf(v.x) | ((u64)f2bf(v.y) << 16)
              | ((u64)f2bf(v.z) << 32) | ((u64)f2bf(v.w) << 48);
        reinterpret_cast<u64*>(o)[i] = r;
    }
}

// ---------------- fused scan v8 ----------------
__device__ __forceinline__ float fsig(float x) { return 1.f / (1.f + __expf(-x)); }
__device__ __forceinline__ float ftanh(float x) {
    return fmaf(-2.f, 1.f / (1.f + __expf(2.f * x)), 1.f);
}
__device__ __forceinline__ float bflo(unsigned u) { return __uint_as_float(u << 16); }
__device__ __forceinline__ float bfhi(unsigned u) { return __uint_as_float(u & 0xffff0000u); }
__device__ __forceinline__ u64 pack_h(unsigned seq, float h) {
    return ((u64)seq << 32) | (u64)__float_as_uint(h);
}
__device__ __forceinline__ u64 poll_h(const u64* p, unsigned need) {
    u64 v = __hip_atomic_load(p, __ATOMIC_RELAXED, __HIP_MEMORY_SCOPE_AGENT);
    while ((unsigned)(v >> 32) < need)
        v = __hip_atomic_load(p, __ATOMIC_RELAXED, __HIP_MEMORY_SCOPE_AGENT);
    return v;
}

__global__ __launch_bounds__(SBS, 1)
void gru_fused(const float* __restrict__ x,      // [T,H]
               float* ys0,                       // [T,H] agent-coherent
               const ushort_t* __restrict__ wbh, // [2][3H][H] bf16 whh
               const ushort_t* __restrict__ wbi, // [2][3H][H] bf16 wih
               const float* __restrict__ bih,    // [2][3H]
               const float* __restrict__ bhh,    // [2][3H]
               float* __restrict__ out,          // [T*H + 2H]
               u64* h0t, u64* h1t,               // [2][H] tagged
               unsigned* flags0) {               // [2][LWG*FSTR]
    const int b   = blockIdx.x;
    const bool L0 = (b & 4) == 0;                       // XCDs 0-3 vs 4-7
    const int g   = L0 ? ((b & 3) * 32 + (b >> 3))
                       : (((b & 7) - 4) * 32 + (b >> 3)); // 0..127
    const int u0  = g * 8;
    const int tid = threadIdx.x;
    const int wv  = tid >> 6;
    const int ln  = tid & 63;

    __shared__ __align__(16) ushort_t lds_wh[24 * HDIM];  // 48KB
    __shared__ __align__(16) ushort_t lds_wi[24 * HDIM];  // 48KB
    __shared__ __align__(16) float lds_hf[HDIM];          // 4KB
    __shared__ __align__(16) float lds_y[2][HDIM];        // 8KB
    __shared__ float lds_gi[2][24];
    __shared__ float lds_gh[24];

    const size_t W3H = (size_t)3 * HDIM * HDIM;
    const ushort_t* whsel = wbh + (L0 ? 0 : W3H);
    const ushort_t* wisel = wbi + (L0 ? 0 : W3H);
    const float*    xsrc  = L0 ? x : ys0;
    u64*            hT    = L0 ? h0t : h1t;

    // ---- load weight slices -> LDS (bf16, 128 uint4 per row) ----
    for (int i = tid; i < 24 * 128; i += SBS) {
        const int r = i >> 7, c = i & 127;
        const size_t gr = (size_t)((r >> 3) * HDIM + u0 + (r & 7)) * HDIM;
        reinterpret_cast<uint4*>(lds_wh)[r * 128 + c] =
            reinterpret_cast<const uint4*>(whsel + gr)[c];
        reinterpret_cast<uint4*>(lds_wi)[r * 128 + c] =
            reinterpret_cast<const uint4*>(wisel + gr)[c];
    }
    // h(0)=0
    reinterpret_cast<float2*>(lds_hf)[tid] = float2{0.f, 0.f};

    // biases (lanes 0..7)
    float c_bir = 0.f, c_biz = 0.f, c_bin = 0.f;
    float c_bhr = 0.f, c_bhz = 0.f, c_bhn = 0.f;
    float h_own = 0.f;
    if (tid < 8) {
        const int u = u0 + tid;
        const float* bi = bih + (L0 ? 0 : 3 * HDIM);
        const float* bh = bhh + (L0 ? 0 : 3 * HDIM);
        c_bir = bi[u]; c_biz = bi[HDIM + u]; c_bin = bi[2 * HDIM + u];
        c_bhr = bh[u]; c_bhz = bh[HDIM + u]; c_bhn = bh[2 * HDIM + u];
    }

    // ---- prologue: stage input(0) ----
    if (wv == 6) {
        if (!L0) {
            const unsigned* f = flags0 + 0 * (LWG * FSTR);
            while (__hip_atomic_load(f + ln * FSTR, __ATOMIC_RELAXED, __HIP_MEMORY_SCOPE_AGENT) < 1u) {}
            while (__hip_atomic_load(f + (ln + 64) * FSTR, __ATOMIC_RELAXED, __HIP_MEMORY_SCOPE_AGENT) < 1u) {}
        }
        const u64* s8 = reinterpret_cast<const u64*>(xsrc);
        u64* d8 = reinterpret_cast<u64*>(lds_y[0]);
#pragma unroll
        for (int k = 0; k < 8; ++k)
            d8[k * 64 + ln] = __hip_atomic_load(s8 + k * 64 + ln, __ATOMIC_RELAXED,
                                                __HIP_MEMORY_SCOPE_AGENT);
    }
    __syncthreads();

    // gi(0) (waves 3-5); stage input(1) (wave 6)
    if (wv >= 3 && wv < 6) {
        const float4* ly4 = reinterpret_cast<const float4*>(lds_y[0]);
        float4 yA = ly4[ln], yB = ly4[64 + ln], yC = ly4[128 + ln], yD = ly4[192 + ln];
        const uint2* wi2 = reinterpret_cast<const uint2*>(lds_wi);
#pragma unroll
        for (int rr = 0; rr < 8; ++rr) {
            const int row = (wv - 3) * 8 + rr;
            const uint2* wr = wi2 + row * 256;
            uint2 w0 = wr[ln], w1 = wr[64 + ln], w2 = wr[128 + ln], w3 = wr[192 + ln];
            float p = 0.f;
            p = fmaf(bflo(w0.x), yA.x, p); p = fmaf(bfhi(w0.x), yA.y, p);
            p = fmaf(bflo(w0.y), yA.z, p); p = fmaf(bfhi(w0.y), yA.w, p);
            p = fmaf(bflo(w1.x), yB.x, p); p = fmaf(bfhi(w1.x), yB.y, p);
            p = fmaf(bflo(w1.y), yB.z, p); p = fmaf(bfhi(w1.y), yB.w, p);
            p = fmaf(bflo(w2.x), yC.x, p); p = fmaf(bfhi(w2.x), yC.y, p);
            p = fmaf(bflo(w2.y), yC.z, p); p = fmaf(bfhi(w2.y), yC.w, p);
            p = fmaf(bflo(w3.x), yD.x, p); p = fmaf(bfhi(w3.x), yD.y, p);
            p = fmaf(bflo(w3.y), yD.z, p); p = fmaf(bfhi(w3.y), yD.w, p);
            p += __shfl_xor(p, 1);  p += __shfl_xor(p, 2);
            p += __shfl_xor(p, 4);  p += __shfl_xor(p, 8);
            p += __shfl_xor(p, 16); p += __shfl_xor(p, 32);
            if (ln == 0) lds_gi[0][row] = p;
        }
    }
    if (wv == 6 && TT > 1) {
        if (!L0) {
            const unsigned* f = flags0 + 1 * (LWG * FSTR);
            while (__hip_atomic_load(f + ln * FSTR, __ATOMIC_RELAXED, __HIP_MEMORY_SCOPE_AGENT) < 2u) {}
            while (__hip_atomic_load(f + (ln + 64) * FSTR, __ATOMIC_RELAXED, __HIP_MEMORY_SCOPE_AGENT) < 2u) {}
        }
        const u64* s8 = reinterpret_cast<const u64*>(xsrc + HDIM);
        u64* d8 = reinterpret_cast<u64*>(lds_y[1]);
#pragma unroll
        for (int k = 0; k < 8; ++k)
            d8[k * 64 + ln] = __hip_atomic_load(s8 + k * 64 + ln, __ATOMIC_RELAXED,
                                                __HIP_MEMORY_SCOPE_AGENT);
    }
    __syncthreads();

    // ---- main loop ----
    for (int t = 0; t < TT; ++t) {
        // phase A
        if (wv < 3) {              // gh = whh(bf16 LDS) . h(t)
            const float4* lh4 = reinterpret_cast<const float4*>(lds_hf);
            float4 hA = lh4[ln], hB = lh4[64 + ln], hC = lh4[128 + ln], hD = lh4[192 + ln];
            const uint2* wh2 = reinterpret_cast<const uint2*>(lds_wh);
#pragma unroll
            for (int rr = 0; rr < 8; ++rr) {
                const int row = wv * 8 + rr;
                const uint2* wr = wh2 + row * 256;
                uint2 w0 = wr[ln], w1 = wr[64 + ln], w2 = wr[128 + ln], w3 = wr[192 + ln];
                float p = 0.f;
                p = fmaf(bflo(w0.x), hA.x, p); p = fmaf(bfhi(w0.x), hA.y, p);
                p = fmaf(bflo(w0.y), hA.z, p); p = fmaf(bfhi(w0.y), hA.w, p);
                p = fmaf(bflo(w1.x), hB.x, p); p = fmaf(bfhi(w1.x), hB.y, p);
                p = fmaf(bflo(w1.y), hB.z, p); p = fmaf(bfhi(w1.y), hB.w, p);
                p = fmaf(bflo(w2.x), hC.x, p); p = fmaf(bfhi(w2.x), hC.y, p);
                p = fmaf(bflo(w2.y), hC.z, p); p = fmaf(bfhi(w2.y), hC.w, p);
                p = fmaf(bflo(w3.x), hD.x, p); p = fmaf(bfhi(w3.x), hD.y, p);
                p = fmaf(bflo(w3.y), hD.z, p); p = fmaf(bfhi(w3.y), hD.w, p);
                p += __shfl_xor(p, 1);  p += __shfl_xor(p, 2);
                p += __shfl_xor(p, 4);  p += __shfl_xor(p, 8);
                p += __shfl_xor(p, 16); p += __shfl_xor(p, 32);
                if (ln == 0) lds_gh[row] = p;
            }
        } else if (wv < 6) {       // gi(t+1) = wih(bf16 LDS) . input(t+1)
            const float4* ly4 = reinterpret_cast<const float4*>(lds_y[(t + 1) & 1]);
            float4 yA = ly4[ln], yB = ly4[64 + ln], yC = ly4[128 + ln], yD = ly4[192 + ln];
            const uint2* wi2 = reinterpret_cast<const uint2*>(lds_wi);
#pragma unroll
            for (int rr = 0; rr < 8; ++rr) {
                const int row = (wv - 3) * 8 + rr;
                const uint2* wr = wi2 + row * 256;
                uint2 w0 = wr[ln], w1 = wr[64 + ln], w2 = wr[128 + ln], w3 = wr[192 + ln];
                float p = 0.f;
                p = fmaf(bflo(w0.x), yA.x, p); p = fmaf(bfhi(w0.x), yA.y, p);
                p = fmaf(bflo(w0.y), yA.z, p); p = fmaf(bfhi(w0.y), yA.w, p);
                p = fmaf(bflo(w1.x), yB.x, p); p = fmaf(bfhi(w1.x), yB.y, p);
                p = fmaf(bflo(w1.y), yB.z, p); p = fmaf(bfhi(w1.y), yB.w, p);
                p = fmaf(bflo(w2.x), yC.x, p); p = fmaf(bfhi(w2.x), yC.y, p);
                p = fmaf(bflo(w2.y), yC.z, p); p = fmaf(bfhi(w2.y), yC.w, p);
                p = fmaf(bflo(w3.x), yD.x, p); p = fmaf(bfhi(w3.x), yD.y, p);
                p = fmaf(bflo(w3.y), yD.z, p); p = fmaf(bfhi(w3.y), yD.w, p);
                p += __shfl_xor(p, 1);  p += __shfl_xor(p, 2);
                p += __shfl_xor(p, 4);  p += __shfl_xor(p, 8);
                p += __shfl_xor(p, 16); p += __shfl_xor(p, 32);
                if (ln == 0) lds_gi[(t + 1) & 1][row] = p;
            }
        } else if (wv == 6) {      // stage input(t+2) -> lds_y[t&1]
            const int s = t + 2;
            if (s < TT) {
                if (!L0) {
                    const unsigned* f = flags0 + (s & 1) * (LWG * FSTR);
                    const unsigned need = (unsigned)(s + 1);
                    while (__hip_atomic_load(f + ln * FSTR, __ATOMIC_RELAXED, __HIP_MEMORY_SCOPE_AGENT) < need) {}
                    while (__hip_atomic_load(f + (ln + 64) * FSTR, __ATOMIC_RELAXED, __HIP_MEMORY_SCOPE_AGENT) < need) {}
                }
                const u64* s8 = reinterpret_cast<const u64*>(xsrc + (size_t)s * HDIM);
                u64* d8 = reinterpret_cast<u64*>(lds_y[t & 1]);
#pragma unroll
                for (int k = 0; k < 8; ++k)
                    d8[k * 64 + ln] = __hip_atomic_load(s8 + k * 64 + ln, __ATOMIC_RELAXED,
                                                        __HIP_MEMORY_SCOPE_AGENT);
            }
        }
        __syncthreads();   // S1

        // phase B: gates (lanes 0..7)
        if (tid < 8) {
            const int u = u0 + tid;
            const float r = fsig(lds_gi[t & 1][tid]      + c_bir + lds_gh[tid]      + c_bhr);
            const float z = fsig(lds_gi[t & 1][8 + tid]  + c_biz + lds_gh[8 + tid]  + c_bhz);
            const float hn = lds_gh[16 + tid] + c_bhn;
            const float n = ftanh(lds_gi[t & 1][16 + tid] + c_bin + r * hn);
            const float h_new = (1.f - z) * n + z * h_own;
            h_own = h_new;
            __hip_atomic_store(hT + ((t + 1) & 1) * HDIM + u,
                               pack_h((unsigned)(t + 1), h_new),
                               __ATOMIC_RELAXED, __HIP_MEMORY_SCOPE_AGENT);
            if (L0) {
                __hip_atomic_store(ys0 + (size_t)t * HDIM + u, h_new,
                                   __ATOMIC_RELAXED, __HIP_MEMORY_SCOPE_AGENT);
            } else {
                out[(size_t)t * HDIM + u] = h_new;
            }
            if (t == TT - 1) out[(size_t)TT * HDIM + (L0 ? 0 : HDIM) + u] = h_new;
        }
        if (L0 && tid == 0) {
            __threadfence();
            __hip_atomic_store(flags0 + (t & 1) * (LWG * FSTR) + g * FSTR,
                               (unsigned)(t + 1),
                               __ATOMIC_RELAXED, __HIP_MEMORY_SCOPE_AGENT);
        }

        // phase D: poll own 2 units of h(t+1) -> lds_hf
        if (t + 1 < TT) {
            const unsigned need = (unsigned)(t + 1);
            const u64* hp = hT + ((t + 1) & 1) * HDIM;
            u64 v0 = poll_h(hp + 2 * tid, need);
            u64 v1 = poll_h(hp + 2 * tid + 1, need);
            float2 hv;
            hv.x = __uint_as_float((unsigned)v0);
            hv.y = __uint_as_float((unsigned)v1);
            reinterpret_cast<float2*>(lds_hf)[tid] = hv;
        }
        __syncthreads();   // S2
    }
}

// ---------------- launch ----------------
extern "C" void kernel_launch(void* const* d_in, const int* in_sizes, int n_in,
                              void* d_out, int out_size, void* d_ws, size_t ws_size,
                              hipStream_t stream) {
    const int*   idx = (const int*)d_in[0];
    const float* emb = (const float*)d_in[1];
    const float* wih = (const float*)d_in[2];
    const float* whh = (const float*)d_in[3];
    const float* bih = (const float*)d_in[4];
    const float* bhh = (const float*)d_in[5];
    float* out = (float*)d_out;

    float* x   = (float*)d_ws;                              // [T,H]
    float* ys0 = x + (size_t)TT * HDIM;                     // [T,H]
    ushort_t* wbh = (ushort_t*)(ys0 + (size_t)TT * HDIM);   // [2*3H*H] bf16
    ushort_t* wbi = wbh + (size_t)2 * 3 * HDIM * HDIM;      // [2*3H*H] bf16
    char* ctrl = (char*)(wbi + (size_t)2 * 3 * HDIM * HDIM);
    u64* h0t = (u64*)ctrl;                                  // [2][H]
    u64* h1t = h0t + 2 * HDIM;                              // [2][H]
    unsigned* flags0 = (unsigned*)(h1t + 2 * HDIM);         // [2][LWG*FSTR]
    size_t ctrl_bytes = (size_t)(4 * HDIM) * 8 + (size_t)(2 * LWG * FSTR) * 4;

    hipMemsetAsync(ctrl, 0, ctrl_bytes, stream);

    embed_kernel<<<TT, 256, 0, stream>>>(idx, emb, x);

    const int n4 = 2 * 3 * HDIM * HDIM / 4;
    conv_bf16<<<(n4 + 255) / 256, 256, 0, stream>>>(whh, wbh, n4);
    conv_bf16<<<(n4 + 255) / 256, 256, 0, stream>>>(wih, wbi, n4);

    gru_fused<<<256, SBS, 0, stream>>>(
        x, ys0, wbh, wbi, bih, bhh, out, h0t, h1t, flags0);
}